// Round 10
// baseline (311.525 us; speedup 1.0000x reference)
//
#include <hip/hip_runtime.h>
#include <math.h>

#define B_ 4
#define K_ 512
#define N_ 4096
#define M_ 4

#define KTHREADS 512
#define SLOTS 8                 // slot = tid & 7 ; rows n0=slot, n1=slot+8
#define SEGS 64                 // seg  = tid >> 3
#define ROWS 16                 // rows per block (SLOTS * 2)
#define CHUNK 1024
#define NCHUNK (N_ / CHUNK)     // 4
#define BIGF 3.0e38f

// ---------------- scalar-only sorting networks (NO arrays -> no allocas -> no scratch) ----
#define CSW(x,y) { float _lo = fminf(x,y); y = fmaxf(x,y); x = _lo; }

// Batcher odd-even mergesort, 8 elements, 19 comparators.
#define SORT8S(s0,s1,s2,s3,s4,s5,s6,s7) \
    CSW(s0,s1) CSW(s2,s3) CSW(s4,s5) CSW(s6,s7) \
    CSW(s0,s2) CSW(s1,s3) CSW(s4,s6) CSW(s5,s7) \
    CSW(s1,s2) CSW(s5,s6) \
    CSW(s0,s4) CSW(s1,s5) CSW(s2,s6) CSW(s3,s7) \
    CSW(s2,s4) CSW(s3,s5) \
    CSW(s1,s2) CSW(s3,s4) CSW(s5,s6)

// K (sorted asc) := lowest-8 of union(K, S) where S sorted asc; result sorted asc.
#define BMERGE8S(K0,K1,K2,K3,K4,K5,K6,K7, S0,S1,S2,S3,S4,S5,S6,S7) \
    K0 = fminf(K0,S7); K1 = fminf(K1,S6); K2 = fminf(K2,S5); K3 = fminf(K3,S4); \
    K4 = fminf(K4,S3); K5 = fminf(K5,S2); K6 = fminf(K6,S1); K7 = fminf(K7,S0); \
    CSW(K0,K4) CSW(K1,K5) CSW(K2,K6) CSW(K3,K7) \
    CSW(K0,K2) CSW(K1,K3) CSW(K4,K6) CSW(K5,K7) \
    CSW(K0,K1) CSW(K2,K3) CSW(K4,K5) CSW(K6,K7)

// butterfly wave-merge step: merge with lane^off partner's sorted list
#define WMERGE(K0,K1,K2,K3,K4,K5,K6,K7, off) { \
    float _b0 = __shfl_xor(K0, off, 64); float _b1 = __shfl_xor(K1, off, 64); \
    float _b2 = __shfl_xor(K2, off, 64); float _b3 = __shfl_xor(K3, off, 64); \
    float _b4 = __shfl_xor(K4, off, 64); float _b5 = __shfl_xor(K5, off, 64); \
    float _b6 = __shfl_xor(K6, off, 64); float _b7 = __shfl_xor(K7, off, 64); \
    BMERGE8S(K0,K1,K2,K3,K4,K5,K6,K7, _b0,_b1,_b2,_b3,_b4,_b5,_b6,_b7) }

// ---------------- Kernel 1: FUSED quota + Cholesky + sample ----------------
// (unchanged — passing, absmax 0.0078)
__global__ __launch_bounds__(512) void fused_kernel(const float* __restrict__ mu_p,
                                                    const float* __restrict__ Sig_p,
                                                    const float* __restrict__ occ,
                                                    const float* __restrict__ mask_parent,
                                                    const float* __restrict__ node_mask,
                                                    const float* __restrict__ z,
                                                    float* __restrict__ out,
                                                    float4* __restrict__ mu4,
                                                    int useF4)
{
    __shared__ double sh_a[K_];                    // pi, then base
    __shared__ double sh_part[32];
    __shared__ alignas(16) double sh_frac[K_];     // exact f64 fracs (fallback path)
    __shared__ alignas(16) float  sh_ffr[K_];      // f32 shadow for the fast rank
    __shared__ float  csf[K_];                     // float cumsum for the search
    __shared__ double Lsh[K_][6];                  // 24 KB Cholesky table
    __shared__ int    sh_wsum[8];
    __shared__ double s_S;
    __shared__ int    s_rem;

    int b  = blockIdx.x >> 3;          // /8
    int rb = blockIdx.x & 7;
    int k  = threadIdx.x;              // 0..511 == parent index

    // ---- quota (np-f64 exact, parallel) ----
    float mk = mask_parent[b * K_ + k];
    bool valid = mk > 0.5f;
    double pi = valid ? (double)occ[b * K_ + k] : 0.0;
    sh_a[k] = pi;
    __syncthreads();

    if (k < 32) {                       // numpy's exact pairwise association
        const double* a = sh_a + (k >> 3) * 128;
        int j = k & 7;
        double r = a[j];
        for (int i = 8; i < 128; i += 8) r += a[j + i];
        sh_part[k] = r;
    }
    __syncthreads();
    if (k == 0) {
        double pw[4];
        #pragma unroll
        for (int blk = 0; blk < 4; ++blk) {
            const double* p = sh_part + blk * 8;
            pw[blk] = ((p[0]+p[1])+(p[2]+p[3]))+((p[4]+p[5])+(p[6]+p[7]));
        }
        s_S = fmax((pw[0]+pw[1])+(pw[2]+pw[3]), 1e-9);
    }
    __syncthreads();

    double raw  = (pi / s_S) * 4096.0;
    double base = floor(raw);
    double frac = valid ? (raw - base) : -1e9;
    sh_frac[k] = frac;
    sh_ffr[k]  = (float)frac;
    __syncthreads();
    sh_a[k] = base;
    __syncthreads();
    if (k < 32) {
        const double* a = sh_a + (k >> 3) * 128;
        int j = k & 7;
        double r = a[j];
        for (int i = 8; i < 128; i += 8) r += a[j + i];
        sh_part[k] = r;
    }
    __syncthreads();
    if (k == 0) {
        double pw[4];
        #pragma unroll
        for (int blk = 0; blk < 4; ++blk) {
            const double* p = sh_part + blk * 8;
            pw[blk] = ((p[0]+p[1])+(p[2]+p[3]))+((p[4]+p[5])+(p[6]+p[7]));
        }
        s_rem = (int)(4096.0 - ((pw[0]+pw[1])+(pw[2]+pw[3])));
    }
    __syncthreads();

    // ---- stable rank in descending frac ----
    int nkv = 0;
    if (valid) {
        float fl = (float)frac;
        int rank = 0, eq = 0;
        const float4* f4 = reinterpret_cast<const float4*>(sh_ffr);
        #pragma unroll 4
        for (int j4 = 0; j4 < K_ / 4; ++j4) {
            float4 q = f4[j4];
            rank += (q.x > fl) ? 1 : 0;  eq += (q.x == fl) ? 1 : 0;
            rank += (q.y > fl) ? 1 : 0;  eq += (q.y == fl) ? 1 : 0;
            rank += (q.z > fl) ? 1 : 0;  eq += (q.z == fl) ? 1 : 0;
            rank += (q.w > fl) ? 1 : 0;  eq += (q.w == fl) ? 1 : 0;
        }
        if (__builtin_expect(eq != 1, 0)) {      // float collision: exact f64 rank
            double f = frac;
            rank = 0;
            for (int j = 0; j < K_; ++j) {
                double fj = sh_frac[j];
                rank += ((fj > f) || (fj == f && j < k)) ? 1 : 0;
            }
        }
        nkv = (int)base + (rank < s_rem ? 1 : 0);
    }

    // ---- inclusive scan: wave shfl scan + cross-wave offsets (integer-exact) ----
    {
        int lane = k & 63;
        int w    = k >> 6;
        int v = nkv;
        #pragma unroll
        for (int off = 1; off < 64; off <<= 1) {
            int t = __shfl_up(v, off, 64);
            v += (lane >= off) ? t : 0;
        }
        if (lane == 63) sh_wsum[w] = v;
        __syncthreads();
        int woff = 0;
        #pragma unroll
        for (int i = 0; i < 7; ++i) woff += (i < w) ? sh_wsum[i] : 0;
        csf[k] = (float)(v + woff);
    }

    // ---- per-parent Cholesky into LDS (identical f64 formula) ----
    {
        const float* S = Sig_p + (size_t)(b * K_ + k) * 9;
        double s00 = (double)S[0] + 1e-6;
        double s01 = 0.5 * ((double)S[1] + (double)S[3]);
        double s02 = 0.5 * ((double)S[2] + (double)S[6]);
        double s11 = (double)S[4] + 1e-6;
        double s12 = 0.5 * ((double)S[5] + (double)S[7]);
        double s22 = (double)S[8] + 1e-6;

        const double eps = 1e-6;
        double l00 = sqrt(fmax(s00, eps));
        double l10 = s01 / fmax(l00, eps);
        double l20 = s02 / fmax(l00, eps);
        double l11 = sqrt(fmax(s11 - l10 * l10, eps));
        double l21 = (s12 - l20 * l10) / fmax(l11, eps);
        double l22 = sqrt(fmax(s22 - l20 * l20 - l21 * l21, eps));

        Lsh[k][0] = l00; Lsh[k][1] = l10; Lsh[k][2] = l20;
        Lsh[k][3] = l11; Lsh[k][4] = l21; Lsh[k][5] = l22;
    }
    __syncthreads();   // covers csf + Lsh writes

    // ---- sample node n (LDS binary search + LDS L) ----
    int n = rb * 512 + k;
    float nf = (float)n;
    int lo = 0, hi = K_;
    while (lo < hi) {
        int mid = (lo + hi) >> 1;
        if (csf[mid] <= nf) lo = mid + 1; else hi = mid;
    }
    int p = lo < (K_ - 1) ? lo : (K_ - 1);

    double l00 = Lsh[p][0], l10 = Lsh[p][1], l20 = Lsh[p][2];
    double l11 = Lsh[p][3], l21 = Lsh[p][4], l22 = Lsh[p][5];

    const float* zp = z + (size_t)(b * N_ + n) * (M_ * 3);
    double bestScore = 1e30;
    int pick = 0;
    #pragma unroll
    for (int m = 0; m < M_; ++m) {
        double z0 = (double)zp[m*3+0], z1 = (double)zp[m*3+1], z2 = (double)zp[m*3+2];
        double maha2 = (z0 * z0 + z1 * z1) + z2 * z2;
        double score = (maha2 <= 7.815) ? (double)m : (1e6 + maha2);
        if (score < bestScore) { bestScore = score; pick = m; }
    }

    double z0 = (double)zp[pick*3+0], z1 = (double)zp[pick*3+1], z2 = (double)zp[pick*3+2];
    const float* mu = mu_p + (size_t)(b * K_ + p) * 3;
    double nm = (double)node_mask[b * N_ + n];
    double c0 = ((double)mu[0] + ((l00 * z0)))                       * nm;
    double c1 = ((double)mu[1] + ((l10 * z0 + l11 * z1)))            * nm;
    double c2 = ((double)mu[2] + ((l20 * z0 + l21 * z1) + l22 * z2)) * nm;

    size_t o = (size_t)(b * N_ + n) * 3;
    float f0 = (float)c0, f1 = (float)c1, f2 = (float)c2;
    out[o + 0] = f0;
    out[o + 1] = f1;
    out[o + 2] = f2;
    if (useF4) {
        float sq = (f0 * f0 + f1 * f1) + f2 * f2;
        mu4[b * N_ + n] = make_float4(f0, f1, f2, sq);
    }
    out[(size_t)B_ * N_ * 12 + (size_t)(b * N_ + n)] = (float)p;   // parent_idx output
}

// ---- staged load phase: 8 back-to-back 16B loads, NO intervening uses ----
#define LD8_G(u) { \
    int col_ = colbase + u * SEGS + seg; \
    float4 q_ = cp[col_]; \
    f##u##x = q_.x; f##u##y = q_.y; f##u##z = q_.z; f##u##w = q_.w; }

#define LD8_S(u) { \
    int col_ = colbase + u * SEGS + seg; \
    size_t o_ = (size_t)(bN + col_) * 3; \
    f##u##x = mu0[o_]; f##u##y = mu0[o_+1]; f##u##z = mu0[o_+2]; \
    f##u##w = (f##u##x*f##u##x + f##u##y*f##u##y) + f##u##z*f##u##z; }

// ---- compute phase: distances for both rows + optional self-mask ----
#define DIST2(u, SQ) \
    s##u = fmaf(a00, f##u##x, fmaf(a01, f##u##y, fmaf(a02, f##u##z, f##u##w))); \
    r##u = fmaf(a10, f##u##x, fmaf(a11, f##u##y, fmaf(a12, f##u##z, f##u##w))); \
    if (SQ) { int col_ = colbase + u * SEGS + seg; \
        s##u = (col_ == n0) ? BIGF : s##u; \
        r##u = (col_ == n1) ? BIGF : r##u; }

#define GROUP8V(LD, SQ) { \
    float f0x,f0y,f0z,f0w, f1x,f1y,f1z,f1w, f2x,f2y,f2z,f2w, f3x,f3y,f3z,f3w; \
    float f4x,f4y,f4z,f4w, f5x,f5y,f5z,f5w, f6x,f6y,f6z,f6w, f7x,f7y,f7z,f7w; \
    LD(0) LD(1) LD(2) LD(3) LD(4) LD(5) LD(6) LD(7) \
    float s0,s1,s2,s3,s4,s5,s6,s7, r0,r1,r2,r3,r4,r5,r6,r7; \
    DIST2(0,SQ) DIST2(1,SQ) DIST2(2,SQ) DIST2(3,SQ) \
    DIST2(4,SQ) DIST2(5,SQ) DIST2(6,SQ) DIST2(7,SQ) \
    SORT8S(s0,s1,s2,s3,s4,s5,s6,s7) \
    BMERGE8S(ka0,ka1,ka2,ka3,ka4,ka5,ka6,ka7, s0,s1,s2,s3,s4,s5,s6,s7) \
    SORT8S(r0,r1,r2,r3,r4,r5,r6,r7) \
    BMERGE8S(kb0,kb1,kb2,kb3,kb4,kb5,kb6,kb7, r0,r1,r2,r3,r4,r5,r6,r7) }

// ================= VISIBLE DIAGNOSTIC PROBES (no stores; asm-sunk; dur > 40 us) =========

// ---- probe VALU x6: pure comparator stream, zero memory. Perfect-issue analytic ~50 us.
#define GROUPVALU(cc) { \
    float s0=fmaf(ka0,0.97f,cc),      s1=fmaf(ka1,0.97f,cc+0.01f); \
    float s2=fmaf(ka2,0.97f,cc+0.02f), s3=fmaf(ka3,0.97f,cc+0.03f); \
    float s4=fmaf(ka4,0.97f,cc+0.04f), s5=fmaf(ka5,0.97f,cc+0.05f); \
    float s6=fmaf(ka6,0.97f,cc+0.06f), s7=fmaf(ka7,0.97f,cc+0.07f); \
    float r0=fmaf(kb0,0.93f,cc),      r1=fmaf(kb1,0.93f,cc+0.01f); \
    float r2=fmaf(kb2,0.93f,cc+0.02f), r3=fmaf(kb3,0.93f,cc+0.03f); \
    float r4=fmaf(kb4,0.93f,cc+0.04f), r5=fmaf(kb5,0.93f,cc+0.05f); \
    float r6=fmaf(kb6,0.93f,cc+0.06f), r7=fmaf(kb7,0.93f,cc+0.07f); \
    SORT8S(s0,s1,s2,s3,s4,s5,s6,s7) \
    BMERGE8S(ka0,ka1,ka2,ka3,ka4,ka5,ka6,ka7, s0,s1,s2,s3,s4,s5,s6,s7) \
    SORT8S(r0,r1,r2,r3,r4,r5,r6,r7) \
    BMERGE8S(kb0,kb1,kb2,kb3,kb4,kb5,kb6,kb7, r0,r1,r2,r3,r4,r5,r6,r7) }

__global__ __launch_bounds__(KTHREADS, 4) void knn_probe_valu6x()
{
    int tid = threadIdx.x;
    float t = (float)tid * 1.0e-3f + (float)blockIdx.x * 1.0e-5f;
    float ka0=t,      ka1=t+1.0f, ka2=t+2.0f, ka3=t+3.0f;
    float ka4=t+4.0f, ka5=t+5.0f, ka6=t+6.0f, ka7=t+7.0f;
    float kb0=t+0.5f, kb1=t+1.5f, kb2=t+2.5f, kb3=t+3.5f;
    float kb4=t+4.5f, kb5=t+5.5f, kb6=t+6.5f, kb7=t+7.5f;
    #pragma unroll 1
    for (int it = 0; it < 6; ++it) {
        float cc = 0.11f + (float)it * 0.013f;
        GROUPVALU(cc)          GROUPVALU(cc+0.10f) GROUPVALU(cc+0.20f) GROUPVALU(cc+0.30f)
        GROUPVALU(cc+0.40f) GROUPVALU(cc+0.50f) GROUPVALU(cc+0.60f) GROUPVALU(cc+0.70f)
    }
    WMERGE(ka0,ka1,ka2,ka3,ka4,ka5,ka6,ka7, 8)
    WMERGE(ka0,ka1,ka2,ka3,ka4,ka5,ka6,ka7, 16)
    WMERGE(ka0,ka1,ka2,ka3,ka4,ka5,ka6,ka7, 32)
    WMERGE(kb0,kb1,kb2,kb3,kb4,kb5,kb6,kb7, 8)
    WMERGE(kb0,kb1,kb2,kb3,kb4,kb5,kb6,kb7, 16)
    WMERGE(kb0,kb1,kb2,kb3,kb4,kb5,kb6,kb7, 32)
    asm volatile("" :: "v"(ka0),"v"(ka1),"v"(ka2),"v"(ka3),"v"(ka4),"v"(ka5),"v"(ka6),"v"(ka7));
    asm volatile("" :: "v"(kb0),"v"(kb1),"v"(kb2),"v"(kb3),"v"(kb4),"v"(kb5),"v"(kb6),"v"(kb7));
}

// ---- probe MEM x12: pure replicated-load stream, no consuming arithmetic.
// Opaque per-iteration offset defeats CSE (compiler must reissue all loads).
#define LDP(u) { \
    int col_ = colbase + u * SEGS + seg; \
    float4 q_ = cp[col_]; \
    asm volatile("" :: "v"(q_.x), "v"(q_.y), "v"(q_.z), "v"(q_.w)); }

__global__ __launch_bounds__(KTHREADS, 4) void knn_probe_mem12x(const float4* __restrict__ mu4)
{
    int b   = blockIdx.x / (N_ / ROWS);
    int tid = threadIdx.x;
    int seg = tid >> 3;
    const float4* cp = mu4 + (size_t)b * N_;
    #pragma unroll 1
    for (int it = 0; it < 12; ++it) {
        int ofs = 0;
        asm volatile("" : "+v"(ofs));          // opaque: addresses unprovable-equal
        #pragma unroll
        for (int c = 0; c < NCHUNK; ++c) {
            { int colbase = c * CHUNK + ofs;
              LDP(0) LDP(1) LDP(2) LDP(3) LDP(4) LDP(5) LDP(6) LDP(7) }
            { int colbase = c * CHUNK + 512 + ofs;
              LDP(0) LDP(1) LDP(2) LDP(3) LDP(4) LDP(5) LDP(6) LDP(7) }
        }
    }
}

// ---------------- Kernel 2: kNN — R7 verbatim (clean: 52 VGPR, zero scratch) -------------
__global__ __launch_bounds__(KTHREADS, 4) void knn_kernel(const float* __restrict__ Sig_p,
                                                          const float* __restrict__ node_mask,
                                                          const float4* __restrict__ mu4,
                                                          int useF4,
                                                          float* __restrict__ out)
{
    __shared__ float  shk[ROWS][8 * 8 + 1];       // 16 x 65 = 4.2 KB wave partials

    int b   = blockIdx.x / (N_ / ROWS);           // 256 blocks per batch
    int rb  = blockIdx.x % (N_ / ROWS);
    int tid = threadIdx.x;
    int slot = tid & (SLOTS - 1);                 // 0..7
    int seg  = tid >> 3;                          // 0..63

    const float* mu0 = out;                       // [B,N,3]
    const float4* cp = mu4 + (size_t)b * N_;
    int bN = b * N_;
    int n0 = rb * ROWS + slot;
    int n1 = n0 + SLOTS;

    float x0, y0, z0v, x1, y1, z1v;
    if (useF4) {
        float4 p0 = cp[n0]; x0 = p0.x; y0 = p0.y; z0v = p0.z;
        float4 p1 = cp[n1]; x1 = p1.x; y1 = p1.y; z1v = p1.z;
    } else {
        size_t so0 = (size_t)(bN + n0) * 3;
        size_t so1 = (size_t)(bN + n1) * 3;
        x0 = mu0[so0]; y0 = mu0[so0+1]; z0v = mu0[so0+2];
        x1 = mu0[so1]; y1 = mu0[so1+1]; z1v = mu0[so1+2];
    }
    float a00 = -2.0f*x0, a01 = -2.0f*y0, a02 = -2.0f*z0v;
    float a10 = -2.0f*x1, a11 = -2.0f*y1, a12 = -2.0f*z1v;

    float ka0=BIGF,ka1=BIGF,ka2=BIGF,ka3=BIGF,ka4=BIGF,ka5=BIGF,ka6=BIGF,ka7=BIGF;
    float kb0=BIGF,kb1=BIGF,kb2=BIGF,kb3=BIGF,kb4=BIGF,kb5=BIGF,kb6=BIGF,kb7=BIGF;

    int selfc = (rb * ROWS) >> 10;                // chunk containing rows n0,n1

    if (useF4) {
        #pragma unroll
        for (int c = 0; c < NCHUNK; ++c) {
            if (c == selfc) {
                { int colbase = c * CHUNK;       GROUP8V(LD8_G, 1) }
                { int colbase = c * CHUNK + 512; GROUP8V(LD8_G, 1) }
            } else {
                { int colbase = c * CHUNK;       GROUP8V(LD8_G, 0) }
                { int colbase = c * CHUNK + 512; GROUP8V(LD8_G, 0) }
            }
        }
    } else {
        #pragma unroll
        for (int c = 0; c < NCHUNK; ++c) {
            if (c == selfc) {
                { int colbase = c * CHUNK;       GROUP8V(LD8_S, 1) }
                { int colbase = c * CHUNK + 512; GROUP8V(LD8_S, 1) }
            } else {
                { int colbase = c * CHUNK;       GROUP8V(LD8_S, 0) }
                { int colbase = c * CHUNK + 512; GROUP8V(LD8_S, 0) }
            }
        }
    }

    // in-wave butterfly merge over the 3 seg bits
    WMERGE(ka0,ka1,ka2,ka3,ka4,ka5,ka6,ka7, 8)
    WMERGE(ka0,ka1,ka2,ka3,ka4,ka5,ka6,ka7, 16)
    WMERGE(ka0,ka1,ka2,ka3,ka4,ka5,ka6,ka7, 32)
    WMERGE(kb0,kb1,kb2,kb3,kb4,kb5,kb6,kb7, 8)
    WMERGE(kb0,kb1,kb2,kb3,kb4,kb5,kb6,kb7, 16)
    WMERGE(kb0,kb1,kb2,kb3,kb4,kb5,kb6,kb7, 32)

    int lane = tid & 63;
    int w    = tid >> 6;                          // wave 0..7
    if (lane < SLOTS) {
        shk[lane][w*8+0] = ka0; shk[lane][w*8+1] = ka1;
        shk[lane][w*8+2] = ka2; shk[lane][w*8+3] = ka3;
        shk[lane][w*8+4] = ka4; shk[lane][w*8+5] = ka5;
        shk[lane][w*8+6] = ka6; shk[lane][w*8+7] = ka7;
        shk[lane+SLOTS][w*8+0] = kb0; shk[lane+SLOTS][w*8+1] = kb1;
        shk[lane+SLOTS][w*8+2] = kb2; shk[lane+SLOTS][w*8+3] = kb3;
        shk[lane+SLOTS][w*8+4] = kb4; shk[lane+SLOTS][w*8+5] = kb5;
        shk[lane+SLOTS][w*8+6] = kb6; shk[lane+SLOTS][w*8+7] = kb7;
    }
    __syncthreads();

    if (tid < ROWS) {                              // one lane per row: 8 sorted lists -> 8
        int r = tid;
        int nn = rb * ROWS + r;
        float e0=BIGF,e1=BIGF,e2=BIGF,e3=BIGF,e4=BIGF,e5=BIGF,e6=BIGF,e7=BIGF;
        #pragma unroll
        for (int w2 = 0; w2 < 8; ++w2) {
            float b0 = shk[r][w2*8+0], b1 = shk[r][w2*8+1];
            float b2 = shk[r][w2*8+2], b3 = shk[r][w2*8+3];
            float b4 = shk[r][w2*8+4], b5 = shk[r][w2*8+5];
            float b6 = shk[r][w2*8+6], b7 = shk[r][w2*8+7];
            BMERGE8S(e0,e1,e2,e3,e4,e5,e6,e7, b0,b1,b2,b3,b4,b5,b6,b7)
        }

        // restore d2 = sqn + s for the selected 8
        float cn;
        if (useF4) {
            cn = cp[nn].w;
        } else {
            size_t so = (size_t)(bN + nn) * 3;
            float xx = mu0[so], yy = mu0[so+1], zz = mu0[so+2];
            cn = (xx*xx + yy*yy) + zz*zz;
        }

        double s0 = sqrt(fmax((double)(cn + e0), 0.0)), s1 = sqrt(fmax((double)(cn + e1), 0.0));
        double s2 = sqrt(fmax((double)(cn + e2), 0.0)), s3 = sqrt(fmax((double)(cn + e3), 0.0));
        double s4 = sqrt(fmax((double)(cn + e4), 0.0)), s5 = sqrt(fmax((double)(cn + e5), 0.0));
        double s6 = sqrt(fmax((double)(cn + e6), 0.0)), s7 = sqrt(fmax((double)(cn + e7), 0.0));
        double d_mean = (((s0 + s1) + (s2 + s3)) + ((s4 + s5) + (s6 + s7))) / 8.0;

        double sigma = fmin(fmax(1.5 * d_mean, 1e-3), 100.0);
        double spacing = sigma * sigma + 1e-6;

        int p = (int)out[(size_t)B_ * N_ * 12 + (size_t)(bN + nn)];
        const float* S = Sig_p + (size_t)(b * K_ + p) * 9;
        double s00 = (double)S[0];
        double s01 = 0.5 * ((double)S[1] + (double)S[3]);
        double s02 = 0.5 * ((double)S[2] + (double)S[6]);
        double s11 = (double)S[4];
        double s12 = 0.5 * ((double)S[5] + (double)S[7]);
        double s22 = (double)S[8];

        const double BETA = 0.85;
        const double OMB  = 1.0 - 0.85;
        double nm = (double)node_mask[bN + nn];

        double d00 = (BETA * (s00 + 1e-6) + OMB * spacing) + 1e-6;
        double d11 = (BETA * (s11 + 1e-6) + OMB * spacing) + 1e-6;
        double d22 = (BETA * (s22 + 1e-6) + OMB * spacing) + 1e-6;
        double o01 = BETA * s01;
        double o02 = BETA * s02;
        double o12 = BETA * s12;

        float* Sg = out + (size_t)B_ * N_ * 3 + (size_t)(bN + nn) * 9;
        Sg[0] = (float)(d00 * nm); Sg[1] = (float)(o01 * nm); Sg[2] = (float)(o02 * nm);
        Sg[3] = (float)(o01 * nm); Sg[4] = (float)(d11 * nm); Sg[5] = (float)(o12 * nm);
        Sg[6] = (float)(o02 * nm); Sg[7] = (float)(o12 * nm); Sg[8] = (float)(d22 * nm);
    }
}

// ---------------- launch ----------------
extern "C" void kernel_launch(void* const* d_in, const int* in_sizes, int n_in,
                              void* d_out, int out_size, void* d_ws, size_t ws_size,
                              hipStream_t stream)
{
    const float* mu_p        = (const float*)d_in[0];
    const float* Sig_p       = (const float*)d_in[1];
    const float* occ         = (const float*)d_in[2];
    const float* mask_parent = (const float*)d_in[3];
    const float* node_mask   = (const float*)d_in[4];
    const float* z           = (const float*)d_in[5];
    float* out = (float*)d_out;

    // float4 mu0 copy (with squared norm in .w) lives in d_ws.
    int useF4 = (ws_size >= (size_t)B_ * N_ * sizeof(float4)) ? 1 : 0;
    float4* mu4 = (float4*)d_ws;

    fused_kernel<<<B_ * 8, 512, 0, stream>>>(mu_p, Sig_p, occ, mask_parent,
                                             node_mask, z, out, mu4, useF4);

    // ---- visible diagnostic probes (store-free, idempotent) ----
    if (useF4) {
        knn_probe_valu6x<<<B_ * (N_ / ROWS), KTHREADS, 0, stream>>>();
        knn_probe_mem12x<<<B_ * (N_ / ROWS), KTHREADS, 0, stream>>>(mu4);
    }

    knn_kernel<<<B_ * (N_ / ROWS), KTHREADS, 0, stream>>>(Sig_p, node_mask,
                                                          mu4, useF4, out);
}

// Round 12
// 48.884 us; speedup vs baseline: 6.3727x; 6.3727x over previous
//
#include <hip/hip_runtime.h>
#include <math.h>

#define B_ 4
#define K_ 512
#define N_ 4096
#define M_ 4

#define KTHREADS 512
#define SLOTS 8                 // slot = tid & 7 ; rows n0=slot, n1=slot+8
#define SEGS 64                 // seg  = tid >> 3
#define ROWS 16                 // rows per block (SLOTS * 2)
#define CHUNK 1024
#define NCHUNK (N_ / CHUNK)     // 4
#define BIGF 3.0e38f

// ---------------- scalar-only sorting networks (NO arrays -> no allocas -> no scratch) ----
#define CSW(x,y) { float _lo = fminf(x,y); y = fmaxf(x,y); x = _lo; }

// Batcher odd-even mergesort, 8 elements, 19 comparators.
#define SORT8S(s0,s1,s2,s3,s4,s5,s6,s7) \
    CSW(s0,s1) CSW(s2,s3) CSW(s4,s5) CSW(s6,s7) \
    CSW(s0,s2) CSW(s1,s3) CSW(s4,s6) CSW(s5,s7) \
    CSW(s1,s2) CSW(s5,s6) \
    CSW(s0,s4) CSW(s1,s5) CSW(s2,s6) CSW(s3,s7) \
    CSW(s2,s4) CSW(s3,s5) \
    CSW(s1,s2) CSW(s3,s4) CSW(s5,s6)

// K (sorted asc) := lowest-8 of union(K, S) where S sorted asc; result sorted asc.
#define BMERGE8S(K0,K1,K2,K3,K4,K5,K6,K7, S0,S1,S2,S3,S4,S5,S6,S7) \
    K0 = fminf(K0,S7); K1 = fminf(K1,S6); K2 = fminf(K2,S5); K3 = fminf(K3,S4); \
    K4 = fminf(K4,S3); K5 = fminf(K5,S2); K6 = fminf(K6,S1); K7 = fminf(K7,S0); \
    CSW(K0,K4) CSW(K1,K5) CSW(K2,K6) CSW(K3,K7) \
    CSW(K0,K2) CSW(K1,K3) CSW(K4,K6) CSW(K5,K7) \
    CSW(K0,K1) CSW(K2,K3) CSW(K4,K5) CSW(K6,K7)

// butterfly wave-merge step: merge with lane^off partner's sorted list
#define WMERGE(K0,K1,K2,K3,K4,K5,K6,K7, off) { \
    float _b0 = __shfl_xor(K0, off, 64); float _b1 = __shfl_xor(K1, off, 64); \
    float _b2 = __shfl_xor(K2, off, 64); float _b3 = __shfl_xor(K3, off, 64); \
    float _b4 = __shfl_xor(K4, off, 64); float _b5 = __shfl_xor(K5, off, 64); \
    float _b6 = __shfl_xor(K6, off, 64); float _b7 = __shfl_xor(K7, off, 64); \
    BMERGE8S(K0,K1,K2,K3,K4,K5,K6,K7, _b0,_b1,_b2,_b3,_b4,_b5,_b6,_b7) }

// ---------------- Kernel 1: FUSED quota + Cholesky + sample ----------------
// (unchanged — passing, absmax 0.0078)
__global__ __launch_bounds__(512) void fused_kernel(const float* __restrict__ mu_p,
                                                    const float* __restrict__ Sig_p,
                                                    const float* __restrict__ occ,
                                                    const float* __restrict__ mask_parent,
                                                    const float* __restrict__ node_mask,
                                                    const float* __restrict__ z,
                                                    float* __restrict__ out,
                                                    float4* __restrict__ mu4,
                                                    int useF4)
{
    __shared__ double sh_a[K_];                    // pi, then base
    __shared__ double sh_part[32];
    __shared__ alignas(16) double sh_frac[K_];     // exact f64 fracs (fallback path)
    __shared__ alignas(16) float  sh_ffr[K_];      // f32 shadow for the fast rank
    __shared__ float  csf[K_];                     // float cumsum for the search
    __shared__ double Lsh[K_][6];                  // 24 KB Cholesky table
    __shared__ int    sh_wsum[8];
    __shared__ double s_S;
    __shared__ int    s_rem;

    int b  = blockIdx.x >> 3;          // /8
    int rb = blockIdx.x & 7;
    int k  = threadIdx.x;              // 0..511 == parent index

    // ---- quota (np-f64 exact, parallel) ----
    float mk = mask_parent[b * K_ + k];
    bool valid = mk > 0.5f;
    double pi = valid ? (double)occ[b * K_ + k] : 0.0;
    sh_a[k] = pi;
    __syncthreads();

    if (k < 32) {                       // numpy's exact pairwise association
        const double* a = sh_a + (k >> 3) * 128;
        int j = k & 7;
        double r = a[j];
        for (int i = 8; i < 128; i += 8) r += a[j + i];
        sh_part[k] = r;
    }
    __syncthreads();
    if (k == 0) {
        double pw[4];
        #pragma unroll
        for (int blk = 0; blk < 4; ++blk) {
            const double* p = sh_part + blk * 8;
            pw[blk] = ((p[0]+p[1])+(p[2]+p[3]))+((p[4]+p[5])+(p[6]+p[7]));
        }
        s_S = fmax((pw[0]+pw[1])+(pw[2]+pw[3]), 1e-9);
    }
    __syncthreads();

    double raw  = (pi / s_S) * 4096.0;
    double base = floor(raw);
    double frac = valid ? (raw - base) : -1e9;
    sh_frac[k] = frac;
    sh_ffr[k]  = (float)frac;
    __syncthreads();
    sh_a[k] = base;
    __syncthreads();
    if (k < 32) {
        const double* a = sh_a + (k >> 3) * 128;
        int j = k & 7;
        double r = a[j];
        for (int i = 8; i < 128; i += 8) r += a[j + i];
        sh_part[k] = r;
    }
    __syncthreads();
    if (k == 0) {
        double pw[4];
        #pragma unroll
        for (int blk = 0; blk < 4; ++blk) {
            const double* p = sh_part + blk * 8;
            pw[blk] = ((p[0]+p[1])+(p[2]+p[3]))+((p[4]+p[5])+(p[6]+p[7]));
        }
        s_rem = (int)(4096.0 - ((pw[0]+pw[1])+(pw[2]+pw[3])));
    }
    __syncthreads();

    // ---- stable rank in descending frac ----
    int nkv = 0;
    if (valid) {
        float fl = (float)frac;
        int rank = 0, eq = 0;
        const float4* f4 = reinterpret_cast<const float4*>(sh_ffr);
        #pragma unroll 4
        for (int j4 = 0; j4 < K_ / 4; ++j4) {
            float4 q = f4[j4];
            rank += (q.x > fl) ? 1 : 0;  eq += (q.x == fl) ? 1 : 0;
            rank += (q.y > fl) ? 1 : 0;  eq += (q.y == fl) ? 1 : 0;
            rank += (q.z > fl) ? 1 : 0;  eq += (q.z == fl) ? 1 : 0;
            rank += (q.w > fl) ? 1 : 0;  eq += (q.w == fl) ? 1 : 0;
        }
        if (__builtin_expect(eq != 1, 0)) {      // float collision: exact f64 rank
            double f = frac;
            rank = 0;
            for (int j = 0; j < K_; ++j) {
                double fj = sh_frac[j];
                rank += ((fj > f) || (fj == f && j < k)) ? 1 : 0;
            }
        }
        nkv = (int)base + (rank < s_rem ? 1 : 0);
    }

    // ---- inclusive scan: wave shfl scan + cross-wave offsets (integer-exact) ----
    {
        int lane = k & 63;
        int w    = k >> 6;
        int v = nkv;
        #pragma unroll
        for (int off = 1; off < 64; off <<= 1) {
            int t = __shfl_up(v, off, 64);
            v += (lane >= off) ? t : 0;
        }
        if (lane == 63) sh_wsum[w] = v;
        __syncthreads();
        int woff = 0;
        #pragma unroll
        for (int i = 0; i < 7; ++i) woff += (i < w) ? sh_wsum[i] : 0;
        csf[k] = (float)(v + woff);
    }

    // ---- per-parent Cholesky into LDS (identical f64 formula) ----
    {
        const float* S = Sig_p + (size_t)(b * K_ + k) * 9;
        double s00 = (double)S[0] + 1e-6;
        double s01 = 0.5 * ((double)S[1] + (double)S[3]);
        double s02 = 0.5 * ((double)S[2] + (double)S[6]);
        double s11 = (double)S[4] + 1e-6;
        double s12 = 0.5 * ((double)S[5] + (double)S[7]);
        double s22 = (double)S[8] + 1e-6;

        const double eps = 1e-6;
        double l00 = sqrt(fmax(s00, eps));
        double l10 = s01 / fmax(l00, eps);
        double l20 = s02 / fmax(l00, eps);
        double l11 = sqrt(fmax(s11 - l10 * l10, eps));
        double l21 = (s12 - l20 * l10) / fmax(l11, eps);
        double l22 = sqrt(fmax(s22 - l20 * l20 - l21 * l21, eps));

        Lsh[k][0] = l00; Lsh[k][1] = l10; Lsh[k][2] = l20;
        Lsh[k][3] = l11; Lsh[k][4] = l21; Lsh[k][5] = l22;
    }
    __syncthreads();   // covers csf + Lsh writes

    // ---- sample node n (LDS binary search + LDS L) ----
    int n = rb * 512 + k;
    float nf = (float)n;
    int lo = 0, hi = K_;
    while (lo < hi) {
        int mid = (lo + hi) >> 1;
        if (csf[mid] <= nf) lo = mid + 1; else hi = mid;
    }
    int p = lo < (K_ - 1) ? lo : (K_ - 1);

    double l00 = Lsh[p][0], l10 = Lsh[p][1], l20 = Lsh[p][2];
    double l11 = Lsh[p][3], l21 = Lsh[p][4], l22 = Lsh[p][5];

    const float* zp = z + (size_t)(b * N_ + n) * (M_ * 3);
    double bestScore = 1e30;
    int pick = 0;
    #pragma unroll
    for (int m = 0; m < M_; ++m) {
        double z0 = (double)zp[m*3+0], z1 = (double)zp[m*3+1], z2 = (double)zp[m*3+2];
        double maha2 = (z0 * z0 + z1 * z1) + z2 * z2;
        double score = (maha2 <= 7.815) ? (double)m : (1e6 + maha2);
        if (score < bestScore) { bestScore = score; pick = m; }
    }

    double z0 = (double)zp[pick*3+0], z1 = (double)zp[pick*3+1], z2 = (double)zp[pick*3+2];
    const float* mu = mu_p + (size_t)(b * K_ + p) * 3;
    double nm = (double)node_mask[b * N_ + n];
    double c0 = ((double)mu[0] + ((l00 * z0)))                       * nm;
    double c1 = ((double)mu[1] + ((l10 * z0 + l11 * z1)))            * nm;
    double c2 = ((double)mu[2] + ((l20 * z0 + l21 * z1) + l22 * z2)) * nm;

    size_t o = (size_t)(b * N_ + n) * 3;
    float f0 = (float)c0, f1 = (float)c1, f2 = (float)c2;
    out[o + 0] = f0;
    out[o + 1] = f1;
    out[o + 2] = f2;
    if (useF4) {
        float sq = (f0 * f0 + f1 * f1) + f2 * f2;
        mu4[b * N_ + n] = make_float4(f0, f1, f2, sq);
    }
    out[(size_t)B_ * N_ * 12 + (size_t)(b * N_ + n)] = (float)p;   // parent_idx output
}

// ---- LDS-sourced staged load phase: 8 back-to-back ds_read_b128.
// lbuf is pre-offset so lbuf[j] corresponds to global column colbase + j. ----
#define LD8_L(u) { \
    float4 q_ = lbuf[u * SEGS + seg]; \
    f##u##x = q_.x; f##u##y = q_.y; f##u##z = q_.z; f##u##w = q_.w; }

// ---- global fallback (no workspace): direct scalar loads ----
#define LD8_S(u) { \
    int col_ = colbase + u * SEGS + seg; \
    size_t o_ = (size_t)(bN + col_) * 3; \
    f##u##x = mu0[o_]; f##u##y = mu0[o_+1]; f##u##z = mu0[o_+2]; \
    f##u##w = (f##u##x*f##u##x + f##u##y*f##u##y) + f##u##z*f##u##z; }

// ---- compute phase: distances for both rows + optional self-mask ----
#define DIST2(u, SQ) \
    s##u = fmaf(a00, f##u##x, fmaf(a01, f##u##y, fmaf(a02, f##u##z, f##u##w))); \
    r##u = fmaf(a10, f##u##x, fmaf(a11, f##u##y, fmaf(a12, f##u##z, f##u##w))); \
    if (SQ) { int col_ = colbase + u * SEGS + seg; \
        s##u = (col_ == n0) ? BIGF : s##u; \
        r##u = (col_ == n1) ? BIGF : r##u; }

#define GROUP8V(LD, SQ) { \
    float f0x,f0y,f0z,f0w, f1x,f1y,f1z,f1w, f2x,f2y,f2z,f2w, f3x,f3y,f3z,f3w; \
    float f4x,f4y,f4z,f4w, f5x,f5y,f5z,f5w, f6x,f6y,f6z,f6w, f7x,f7y,f7z,f7w; \
    LD(0) LD(1) LD(2) LD(3) LD(4) LD(5) LD(6) LD(7) \
    float s0,s1,s2,s3,s4,s5,s6,s7, r0,r1,r2,r3,r4,r5,r6,r7; \
    DIST2(0,SQ) DIST2(1,SQ) DIST2(2,SQ) DIST2(3,SQ) \
    DIST2(4,SQ) DIST2(5,SQ) DIST2(6,SQ) DIST2(7,SQ) \
    SORT8S(s0,s1,s2,s3,s4,s5,s6,s7) \
    BMERGE8S(ka0,ka1,ka2,ka3,ka4,ka5,ka6,ka7, s0,s1,s2,s3,s4,s5,s6,s7) \
    SORT8S(r0,r1,r2,r3,r4,r5,r6,r7) \
    BMERGE8S(kb0,kb1,kb2,kb3,kb4,kb5,kb6,kb7, r0,r1,r2,r3,r4,r5,r6,r7) }

// one double-buffered chunk step: issue next-chunk global loads (hidden under compute),
// compute current chunk from LDS (lbuf pre-offset per half!), ds_write next, ONE barrier.
// R11 bug: lbuf lacked the +512 offset for the second half-group -> half of every chunk
// scored against the wrong columns. Fixed: lbuf = chk[cur] (+512) matches colbase.
#define CHUNK_STEP(c, cur, nxt, LAST) { \
    float4 st0, st1; \
    if (!(LAST)) { st0 = cp[(c+1)*CHUNK + tid]; st1 = cp[(c+1)*CHUNK + 512 + tid]; } \
    if ((c) == selfc) { \
        { int colbase = (c)*CHUNK;       const float4* lbuf = chk[cur];       GROUP8V(LD8_L, 1) } \
        { int colbase = (c)*CHUNK + 512; const float4* lbuf = chk[cur] + 512; GROUP8V(LD8_L, 1) } \
    } else { \
        { int colbase = (c)*CHUNK;       const float4* lbuf = chk[cur];       GROUP8V(LD8_L, 0) } \
        { int colbase = (c)*CHUNK + 512; const float4* lbuf = chk[cur] + 512; GROUP8V(LD8_L, 0) } \
    } \
    if (!(LAST)) { \
        chk[nxt][tid]       = st0; \
        chk[nxt][tid + 512] = st1; \
        __syncthreads(); \
    } }

// ---------------- Kernel 2: kNN — LDS double-buffered chunks, 1 barrier/chunk ----------
// R10 probes: L1 load-return pipe = ~17.6 cy per 1KB wave-load (probe_mem12x 180us/12x
// at 93% occ) -> ~13.7us of the 40us kernel is return-path time, poorly overlapped with
// the ~14us VALU stream. LDS return is 2x (128 B/cy) and a separate pipe: stage each
// 16KB chunk once, read via ds_read_b128. Double-buffer hides stage latency; one
// barrier per chunk.
__global__ __launch_bounds__(KTHREADS, 4) void knn_kernel(const float* __restrict__ Sig_p,
                                                          const float* __restrict__ node_mask,
                                                          const float4* __restrict__ mu4,
                                                          int useF4,
                                                          float* __restrict__ out)
{
    __shared__ float4 chk[2][CHUNK];              // 32 KB double-buffered columns
    __shared__ float  shk[ROWS][8 * 8 + 1];       // 4.2 KB wave partials

    int b   = blockIdx.x / (N_ / ROWS);           // 256 blocks per batch
    int rb  = blockIdx.x % (N_ / ROWS);
    int tid = threadIdx.x;
    int slot = tid & (SLOTS - 1);                 // 0..7
    int seg  = tid >> 3;                          // 0..63

    const float* mu0 = out;                       // [B,N,3]
    const float4* cp = mu4 + (size_t)b * N_;
    int bN = b * N_;
    int n0 = rb * ROWS + slot;
    int n1 = n0 + SLOTS;

    float x0, y0, z0v, x1, y1, z1v;
    if (useF4) {
        float4 p0 = cp[n0]; x0 = p0.x; y0 = p0.y; z0v = p0.z;
        float4 p1 = cp[n1]; x1 = p1.x; y1 = p1.y; z1v = p1.z;
    } else {
        size_t so0 = (size_t)(bN + n0) * 3;
        size_t so1 = (size_t)(bN + n1) * 3;
        x0 = mu0[so0]; y0 = mu0[so0+1]; z0v = mu0[so0+2];
        x1 = mu0[so1]; y1 = mu0[so1+1]; z1v = mu0[so1+2];
    }
    float a00 = -2.0f*x0, a01 = -2.0f*y0, a02 = -2.0f*z0v;
    float a10 = -2.0f*x1, a11 = -2.0f*y1, a12 = -2.0f*z1v;

    float ka0=BIGF,ka1=BIGF,ka2=BIGF,ka3=BIGF,ka4=BIGF,ka5=BIGF,ka6=BIGF,ka7=BIGF;
    float kb0=BIGF,kb1=BIGF,kb2=BIGF,kb3=BIGF,kb4=BIGF,kb5=BIGF,kb6=BIGF,kb7=BIGF;

    int selfc = (rb * ROWS) >> 10;                // chunk containing rows n0,n1

    if (useF4) {
        // prologue: stage chunk 0
        chk[0][tid]       = cp[tid];
        chk[0][tid + 512] = cp[tid + 512];
        __syncthreads();

        CHUNK_STEP(0, 0, 1, 0)
        CHUNK_STEP(1, 1, 0, 0)
        CHUNK_STEP(2, 0, 1, 0)
        CHUNK_STEP(3, 1, 0, 1)
    } else {
        #pragma unroll
        for (int c = 0; c < NCHUNK; ++c) {
            if (c == selfc) {
                { int colbase = c * CHUNK;       GROUP8V(LD8_S, 1) }
                { int colbase = c * CHUNK + 512; GROUP8V(LD8_S, 1) }
            } else {
                { int colbase = c * CHUNK;       GROUP8V(LD8_S, 0) }
                { int colbase = c * CHUNK + 512; GROUP8V(LD8_S, 0) }
            }
        }
    }

    // in-wave butterfly merge over the 3 seg bits
    WMERGE(ka0,ka1,ka2,ka3,ka4,ka5,ka6,ka7, 8)
    WMERGE(ka0,ka1,ka2,ka3,ka4,ka5,ka6,ka7, 16)
    WMERGE(ka0,ka1,ka2,ka3,ka4,ka5,ka6,ka7, 32)
    WMERGE(kb0,kb1,kb2,kb3,kb4,kb5,kb6,kb7, 8)
    WMERGE(kb0,kb1,kb2,kb3,kb4,kb5,kb6,kb7, 16)
    WMERGE(kb0,kb1,kb2,kb3,kb4,kb5,kb6,kb7, 32)

    int lane = tid & 63;
    int w    = tid >> 6;                          // wave 0..7
    if (lane < SLOTS) {
        shk[lane][w*8+0] = ka0; shk[lane][w*8+1] = ka1;
        shk[lane][w*8+2] = ka2; shk[lane][w*8+3] = ka3;
        shk[lane][w*8+4] = ka4; shk[lane][w*8+5] = ka5;
        shk[lane][w*8+6] = ka6; shk[lane][w*8+7] = ka7;
        shk[lane+SLOTS][w*8+0] = kb0; shk[lane+SLOTS][w*8+1] = kb1;
        shk[lane+SLOTS][w*8+2] = kb2; shk[lane+SLOTS][w*8+3] = kb3;
        shk[lane+SLOTS][w*8+4] = kb4; shk[lane+SLOTS][w*8+5] = kb5;
        shk[lane+SLOTS][w*8+6] = kb6; shk[lane+SLOTS][w*8+7] = kb7;
    }
    __syncthreads();

    if (tid < ROWS) {                              // one lane per row: 8 sorted lists -> 8
        int r = tid;
        int nn = rb * ROWS + r;
        float e0=BIGF,e1=BIGF,e2=BIGF,e3=BIGF,e4=BIGF,e5=BIGF,e6=BIGF,e7=BIGF;
        #pragma unroll
        for (int w2 = 0; w2 < 8; ++w2) {
            float b0 = shk[r][w2*8+0], b1 = shk[r][w2*8+1];
            float b2 = shk[r][w2*8+2], b3 = shk[r][w2*8+3];
            float b4 = shk[r][w2*8+4], b5 = shk[r][w2*8+5];
            float b6 = shk[r][w2*8+6], b7 = shk[r][w2*8+7];
            BMERGE8S(e0,e1,e2,e3,e4,e5,e6,e7, b0,b1,b2,b3,b4,b5,b6,b7)
        }

        // restore d2 = sqn + s for the selected 8
        float cn;
        if (useF4) {
            cn = cp[nn].w;
        } else {
            size_t so = (size_t)(bN + nn) * 3;
            float xx = mu0[so], yy = mu0[so+1], zz = mu0[so+2];
            cn = (xx*xx + yy*yy) + zz*zz;
        }

        double s0 = sqrt(fmax((double)(cn + e0), 0.0)), s1 = sqrt(fmax((double)(cn + e1), 0.0));
        double s2 = sqrt(fmax((double)(cn + e2), 0.0)), s3 = sqrt(fmax((double)(cn + e3), 0.0));
        double s4 = sqrt(fmax((double)(cn + e4), 0.0)), s5 = sqrt(fmax((double)(cn + e5), 0.0));
        double s6 = sqrt(fmax((double)(cn + e6), 0.0)), s7 = sqrt(fmax((double)(cn + e7), 0.0));
        double d_mean = (((s0 + s1) + (s2 + s3)) + ((s4 + s5) + (s6 + s7))) / 8.0;

        double sigma = fmin(fmax(1.5 * d_mean, 1e-3), 100.0);
        double spacing = sigma * sigma + 1e-6;

        int p = (int)out[(size_t)B_ * N_ * 12 + (size_t)(bN + nn)];
        const float* S = Sig_p + (size_t)(b * K_ + p) * 9;
        double s00 = (double)S[0];
        double s01 = 0.5 * ((double)S[1] + (double)S[3]);
        double s02 = 0.5 * ((double)S[2] + (double)S[6]);
        double s11 = (double)S[4];
        double s12 = 0.5 * ((double)S[5] + (double)S[7]);
        double s22 = (double)S[8];

        const double BETA = 0.85;
        const double OMB  = 1.0 - 0.85;
        double nm = (double)node_mask[bN + nn];

        double d00 = (BETA * (s00 + 1e-6) + OMB * spacing) + 1e-6;
        double d11 = (BETA * (s11 + 1e-6) + OMB * spacing) + 1e-6;
        double d22 = (BETA * (s22 + 1e-6) + OMB * spacing) + 1e-6;
        double o01 = BETA * s01;
        double o02 = BETA * s02;
        double o12 = BETA * s12;

        float* Sg = out + (size_t)B_ * N_ * 3 + (size_t)(bN + nn) * 9;
        Sg[0] = (float)(d00 * nm); Sg[1] = (float)(o01 * nm); Sg[2] = (float)(o02 * nm);
        Sg[3] = (float)(o01 * nm); Sg[4] = (float)(d11 * nm); Sg[5] = (float)(o12 * nm);
        Sg[6] = (float)(o02 * nm); Sg[7] = (float)(o12 * nm); Sg[8] = (float)(d22 * nm);
    }
}

// ---------------- launch ----------------
extern "C" void kernel_launch(void* const* d_in, const int* in_sizes, int n_in,
                              void* d_out, int out_size, void* d_ws, size_t ws_size,
                              hipStream_t stream)
{
    const float* mu_p        = (const float*)d_in[0];
    const float* Sig_p       = (const float*)d_in[1];
    const float* occ         = (const float*)d_in[2];
    const float* mask_parent = (const float*)d_in[3];
    const float* node_mask   = (const float*)d_in[4];
    const float* z           = (const float*)d_in[5];
    float* out = (float*)d_out;

    // float4 mu0 copy (with squared norm in .w) lives in d_ws.
    int useF4 = (ws_size >= (size_t)B_ * N_ * sizeof(float4)) ? 1 : 0;
    float4* mu4 = (float4*)d_ws;

    fused_kernel<<<B_ * 8, 512, 0, stream>>>(mu_p, Sig_p, occ, mask_parent,
                                             node_mask, z, out, mu4, useF4);
    knn_kernel<<<B_ * (N_ / ROWS), KTHREADS, 0, stream>>>(Sig_p, node_mask,
                                                          mu4, useF4, out);
}

// Round 13
// 47.248 us; speedup vs baseline: 6.5933x; 1.0346x over previous
//
#include <hip/hip_runtime.h>
#include <math.h>

#define B_ 4
#define K_ 512
#define N_ 4096
#define M_ 4

#define KTHREADS 512
#define SLOTS 8                 // slot = tid & 7 ; rows n0=slot, n1=slot+8
#define SEGS 64                 // seg  = tid >> 3
#define ROWS 16                 // rows per block (SLOTS * 2)
#define CHUNK 1024
#define NCHUNK (N_ / CHUNK)     // 4
#define BIGF 3.0e38f

// ---------------- scalar-only sorting networks (NO arrays -> no allocas -> no scratch) ----
#define CSW(x,y) { float _lo = fminf(x,y); y = fmaxf(x,y); x = _lo; }

// Batcher odd-even mergesort, 8 elements, 19 comparators.
#define SORT8S(s0,s1,s2,s3,s4,s5,s6,s7) \
    CSW(s0,s1) CSW(s2,s3) CSW(s4,s5) CSW(s6,s7) \
    CSW(s0,s2) CSW(s1,s3) CSW(s4,s6) CSW(s5,s7) \
    CSW(s1,s2) CSW(s5,s6) \
    CSW(s0,s4) CSW(s1,s5) CSW(s2,s6) CSW(s3,s7) \
    CSW(s2,s4) CSW(s3,s5) \
    CSW(s1,s2) CSW(s3,s4) CSW(s5,s6)

// K (sorted asc) := lowest-8 of union(K, S) where S sorted asc; result sorted asc.
#define BMERGE8S(K0,K1,K2,K3,K4,K5,K6,K7, S0,S1,S2,S3,S4,S5,S6,S7) \
    K0 = fminf(K0,S7); K1 = fminf(K1,S6); K2 = fminf(K2,S5); K3 = fminf(K3,S4); \
    K4 = fminf(K4,S3); K5 = fminf(K5,S2); K6 = fminf(K6,S1); K7 = fminf(K7,S0); \
    CSW(K0,K4) CSW(K1,K5) CSW(K2,K6) CSW(K3,K7) \
    CSW(K0,K2) CSW(K1,K3) CSW(K4,K6) CSW(K5,K7) \
    CSW(K0,K1) CSW(K2,K3) CSW(K4,K5) CSW(K6,K7)

// butterfly wave-merge step: merge with lane^off partner's sorted list
#define WMERGE(K0,K1,K2,K3,K4,K5,K6,K7, off) { \
    float _b0 = __shfl_xor(K0, off, 64); float _b1 = __shfl_xor(K1, off, 64); \
    float _b2 = __shfl_xor(K2, off, 64); float _b3 = __shfl_xor(K3, off, 64); \
    float _b4 = __shfl_xor(K4, off, 64); float _b5 = __shfl_xor(K5, off, 64); \
    float _b6 = __shfl_xor(K6, off, 64); float _b7 = __shfl_xor(K7, off, 64); \
    BMERGE8S(K0,K1,K2,K3,K4,K5,K6,K7, _b0,_b1,_b2,_b3,_b4,_b5,_b6,_b7) }

// ---------------- Kernel 1: FUSED quota + Cholesky + sample ----------------
// (unchanged — passing, absmax 0.0078)
__global__ __launch_bounds__(512) void fused_kernel(const float* __restrict__ mu_p,
                                                    const float* __restrict__ Sig_p,
                                                    const float* __restrict__ occ,
                                                    const float* __restrict__ mask_parent,
                                                    const float* __restrict__ node_mask,
                                                    const float* __restrict__ z,
                                                    float* __restrict__ out,
                                                    float4* __restrict__ mu4,
                                                    int useF4)
{
    __shared__ double sh_a[K_];                    // pi, then base
    __shared__ double sh_part[32];
    __shared__ alignas(16) double sh_frac[K_];     // exact f64 fracs (fallback path)
    __shared__ alignas(16) float  sh_ffr[K_];      // f32 shadow for the fast rank
    __shared__ float  csf[K_];                     // float cumsum for the search
    __shared__ double Lsh[K_][6];                  // 24 KB Cholesky table
    __shared__ int    sh_wsum[8];
    __shared__ double s_S;
    __shared__ int    s_rem;

    int b  = blockIdx.x >> 3;          // /8
    int rb = blockIdx.x & 7;
    int k  = threadIdx.x;              // 0..511 == parent index

    // ---- quota (np-f64 exact, parallel) ----
    float mk = mask_parent[b * K_ + k];
    bool valid = mk > 0.5f;
    double pi = valid ? (double)occ[b * K_ + k] : 0.0;
    sh_a[k] = pi;
    __syncthreads();

    if (k < 32) {                       // numpy's exact pairwise association
        const double* a = sh_a + (k >> 3) * 128;
        int j = k & 7;
        double r = a[j];
        for (int i = 8; i < 128; i += 8) r += a[j + i];
        sh_part[k] = r;
    }
    __syncthreads();
    if (k == 0) {
        double pw[4];
        #pragma unroll
        for (int blk = 0; blk < 4; ++blk) {
            const double* p = sh_part + blk * 8;
            pw[blk] = ((p[0]+p[1])+(p[2]+p[3]))+((p[4]+p[5])+(p[6]+p[7]));
        }
        s_S = fmax((pw[0]+pw[1])+(pw[2]+pw[3]), 1e-9);
    }
    __syncthreads();

    double raw  = (pi / s_S) * 4096.0;
    double base = floor(raw);
    double frac = valid ? (raw - base) : -1e9;
    sh_frac[k] = frac;
    sh_ffr[k]  = (float)frac;
    __syncthreads();
    sh_a[k] = base;
    __syncthreads();
    if (k < 32) {
        const double* a = sh_a + (k >> 3) * 128;
        int j = k & 7;
        double r = a[j];
        for (int i = 8; i < 128; i += 8) r += a[j + i];
        sh_part[k] = r;
    }
    __syncthreads();
    if (k == 0) {
        double pw[4];
        #pragma unroll
        for (int blk = 0; blk < 4; ++blk) {
            const double* p = sh_part + blk * 8;
            pw[blk] = ((p[0]+p[1])+(p[2]+p[3]))+((p[4]+p[5])+(p[6]+p[7]));
        }
        s_rem = (int)(4096.0 - ((pw[0]+pw[1])+(pw[2]+pw[3])));
    }
    __syncthreads();

    // ---- stable rank in descending frac ----
    int nkv = 0;
    if (valid) {
        float fl = (float)frac;
        int rank = 0, eq = 0;
        const float4* f4 = reinterpret_cast<const float4*>(sh_ffr);
        #pragma unroll 4
        for (int j4 = 0; j4 < K_ / 4; ++j4) {
            float4 q = f4[j4];
            rank += (q.x > fl) ? 1 : 0;  eq += (q.x == fl) ? 1 : 0;
            rank += (q.y > fl) ? 1 : 0;  eq += (q.y == fl) ? 1 : 0;
            rank += (q.z > fl) ? 1 : 0;  eq += (q.z == fl) ? 1 : 0;
            rank += (q.w > fl) ? 1 : 0;  eq += (q.w == fl) ? 1 : 0;
        }
        if (__builtin_expect(eq != 1, 0)) {      // float collision: exact f64 rank
            double f = frac;
            rank = 0;
            for (int j = 0; j < K_; ++j) {
                double fj = sh_frac[j];
                rank += ((fj > f) || (fj == f && j < k)) ? 1 : 0;
            }
        }
        nkv = (int)base + (rank < s_rem ? 1 : 0);
    }

    // ---- inclusive scan: wave shfl scan + cross-wave offsets (integer-exact) ----
    {
        int lane = k & 63;
        int w    = k >> 6;
        int v = nkv;
        #pragma unroll
        for (int off = 1; off < 64; off <<= 1) {
            int t = __shfl_up(v, off, 64);
            v += (lane >= off) ? t : 0;
        }
        if (lane == 63) sh_wsum[w] = v;
        __syncthreads();
        int woff = 0;
        #pragma unroll
        for (int i = 0; i < 7; ++i) woff += (i < w) ? sh_wsum[i] : 0;
        csf[k] = (float)(v + woff);
    }

    // ---- per-parent Cholesky into LDS (identical f64 formula) ----
    {
        const float* S = Sig_p + (size_t)(b * K_ + k) * 9;
        double s00 = (double)S[0] + 1e-6;
        double s01 = 0.5 * ((double)S[1] + (double)S[3]);
        double s02 = 0.5 * ((double)S[2] + (double)S[6]);
        double s11 = (double)S[4] + 1e-6;
        double s12 = 0.5 * ((double)S[5] + (double)S[7]);
        double s22 = (double)S[8] + 1e-6;

        const double eps = 1e-6;
        double l00 = sqrt(fmax(s00, eps));
        double l10 = s01 / fmax(l00, eps);
        double l20 = s02 / fmax(l00, eps);
        double l11 = sqrt(fmax(s11 - l10 * l10, eps));
        double l21 = (s12 - l20 * l10) / fmax(l11, eps);
        double l22 = sqrt(fmax(s22 - l20 * l20 - l21 * l21, eps));

        Lsh[k][0] = l00; Lsh[k][1] = l10; Lsh[k][2] = l20;
        Lsh[k][3] = l11; Lsh[k][4] = l21; Lsh[k][5] = l22;
    }
    __syncthreads();   // covers csf + Lsh writes

    // ---- sample node n (LDS binary search + LDS L) ----
    int n = rb * 512 + k;
    float nf = (float)n;
    int lo = 0, hi = K_;
    while (lo < hi) {
        int mid = (lo + hi) >> 1;
        if (csf[mid] <= nf) lo = mid + 1; else hi = mid;
    }
    int p = lo < (K_ - 1) ? lo : (K_ - 1);

    double l00 = Lsh[p][0], l10 = Lsh[p][1], l20 = Lsh[p][2];
    double l11 = Lsh[p][3], l21 = Lsh[p][4], l22 = Lsh[p][5];

    const float* zp = z + (size_t)(b * N_ + n) * (M_ * 3);
    double bestScore = 1e30;
    int pick = 0;
    #pragma unroll
    for (int m = 0; m < M_; ++m) {
        double z0 = (double)zp[m*3+0], z1 = (double)zp[m*3+1], z2 = (double)zp[m*3+2];
        double maha2 = (z0 * z0 + z1 * z1) + z2 * z2;
        double score = (maha2 <= 7.815) ? (double)m : (1e6 + maha2);
        if (score < bestScore) { bestScore = score; pick = m; }
    }

    double z0 = (double)zp[pick*3+0], z1 = (double)zp[pick*3+1], z2 = (double)zp[pick*3+2];
    const float* mu = mu_p + (size_t)(b * K_ + p) * 3;
    double nm = (double)node_mask[b * N_ + n];
    double c0 = ((double)mu[0] + ((l00 * z0)))                       * nm;
    double c1 = ((double)mu[1] + ((l10 * z0 + l11 * z1)))            * nm;
    double c2 = ((double)mu[2] + ((l20 * z0 + l21 * z1) + l22 * z2)) * nm;

    size_t o = (size_t)(b * N_ + n) * 3;
    float f0 = (float)c0, f1 = (float)c1, f2 = (float)c2;
    out[o + 0] = f0;
    out[o + 1] = f1;
    out[o + 2] = f2;
    if (useF4) {
        float sq = (f0 * f0 + f1 * f1) + f2 * f2;
        mu4[b * N_ + n] = make_float4(f0, f1, f2, sq);
    }
    out[(size_t)B_ * N_ * 12 + (size_t)(b * N_ + n)] = (float)p;   // parent_idx output
}

// one column u of the current 8-batch, read DIRECT FROM GLOBAL (L1/L2-resident 64 KB):
// cp = mu4 + b*N_ (float4 with sq in .w). col = colbase + u*SEGS + seg.
#define LOADU_G(u, SQ) { \
    int col_ = colbase + u * SEGS + seg; \
    float4 q_ = cp[col_]; \
    s##u = fmaf(a00, q_.x, fmaf(a01, q_.y, fmaf(a02, q_.z, q_.w))); \
    r##u = fmaf(a10, q_.x, fmaf(a11, q_.y, fmaf(a12, q_.z, q_.w))); \
    if (SQ) { \
        s##u = (col_ == n0) ? BIGF : s##u; \
        r##u = (col_ == n1) ? BIGF : r##u; } }

// fallback path (no float4 workspace): scalar mu0 reads + inline sq
#define LOADU_S(u, SQ) { \
    int col_ = colbase + u * SEGS + seg; \
    size_t o_ = (size_t)(bN + col_) * 3; \
    float qx_ = mu0[o_], qy_ = mu0[o_+1], qz_ = mu0[o_+2]; \
    float qw_ = (qx_*qx_ + qy_*qy_) + qz_*qz_; \
    s##u = fmaf(a00, qx_, fmaf(a01, qy_, fmaf(a02, qz_, qw_))); \
    r##u = fmaf(a10, qx_, fmaf(a11, qy_, fmaf(a12, qz_, qw_))); \
    if (SQ) { \
        s##u = (col_ == n0) ? BIGF : s##u; \
        r##u = (col_ == n1) ? BIGF : r##u; } }

#define GROUP8(LD, SQ) { \
    float s0,s1,s2,s3,s4,s5,s6,s7, r0,r1,r2,r3,r4,r5,r6,r7; \
    LD(0,SQ) LD(1,SQ) LD(2,SQ) LD(3,SQ) \
    LD(4,SQ) LD(5,SQ) LD(6,SQ) LD(7,SQ) \
    SORT8S(s0,s1,s2,s3,s4,s5,s6,s7) \
    BMERGE8S(ka0,ka1,ka2,ka3,ka4,ka5,ka6,ka7, s0,s1,s2,s3,s4,s5,s6,s7) \
    SORT8S(r0,r1,r2,r3,r4,r5,r6,r7) \
    BMERGE8S(kb0,kb1,kb2,kb3,kb4,kb5,kb6,kb7, r0,r1,r2,r3,r4,r5,r6,r7) }

// ---------------- Kernel 2: kNN — R5 structure (best measured: 47.15 total), USEF4
// templated so only ONE load path is compiled (halves the fully-unrolled body vs the
// runtime-branch version; ~10 KB hot loop in the 32 KB I$). Direct global reads: the
// 64 KB mu4 working set is L1/L2-resident; R12 proved LDS sourcing is equivalent (null),
// and probes show the kernel sits at the comparator-stream issue ceiling (~60%).
template<int USEF4>
__global__ __launch_bounds__(KTHREADS, 4) void knn_kernel(const float* __restrict__ Sig_p,
                                                          const float* __restrict__ node_mask,
                                                          const float4* __restrict__ mu4,
                                                          float* __restrict__ out)
{
    __shared__ float  shk[ROWS][8 * 8 + 1];       // 16 x 65 = 4.2 KB wave partials

    int b   = blockIdx.x / (N_ / ROWS);           // 256 blocks per batch
    int rb  = blockIdx.x % (N_ / ROWS);
    int tid = threadIdx.x;
    int slot = tid & (SLOTS - 1);                 // 0..7
    int seg  = tid >> 3;                          // 0..63

    const float* mu0 = out;                       // [B,N,3]
    const float4* cp = mu4 + (size_t)b * N_;
    int bN = b * N_;
    int n0 = rb * ROWS + slot;
    int n1 = n0 + SLOTS;

    float x0, y0, z0v, x1, y1, z1v;
    if constexpr (USEF4) {
        float4 p0 = cp[n0]; x0 = p0.x; y0 = p0.y; z0v = p0.z;
        float4 p1 = cp[n1]; x1 = p1.x; y1 = p1.y; z1v = p1.z;
    } else {
        size_t so0 = (size_t)(bN + n0) * 3;
        size_t so1 = (size_t)(bN + n1) * 3;
        x0 = mu0[so0]; y0 = mu0[so0+1]; z0v = mu0[so0+2];
        x1 = mu0[so1]; y1 = mu0[so1+1]; z1v = mu0[so1+2];
    }
    float a00 = -2.0f*x0, a01 = -2.0f*y0, a02 = -2.0f*z0v;
    float a10 = -2.0f*x1, a11 = -2.0f*y1, a12 = -2.0f*z1v;

    float ka0=BIGF,ka1=BIGF,ka2=BIGF,ka3=BIGF,ka4=BIGF,ka5=BIGF,ka6=BIGF,ka7=BIGF;
    float kb0=BIGF,kb1=BIGF,kb2=BIGF,kb3=BIGF,kb4=BIGF,kb5=BIGF,kb6=BIGF,kb7=BIGF;

    int selfc = (rb * ROWS) >> 10;                // chunk containing rows n0,n1

    if constexpr (USEF4) {
        #pragma unroll
        for (int c = 0; c < NCHUNK; ++c) {
            if (c == selfc) {
                { int colbase = c * CHUNK;       GROUP8(LOADU_G, 1) }
                { int colbase = c * CHUNK + 512; GROUP8(LOADU_G, 1) }
            } else {
                { int colbase = c * CHUNK;       GROUP8(LOADU_G, 0) }
                { int colbase = c * CHUNK + 512; GROUP8(LOADU_G, 0) }
            }
        }
    } else {
        #pragma unroll
        for (int c = 0; c < NCHUNK; ++c) {
            if (c == selfc) {
                { int colbase = c * CHUNK;       GROUP8(LOADU_S, 1) }
                { int colbase = c * CHUNK + 512; GROUP8(LOADU_S, 1) }
            } else {
                { int colbase = c * CHUNK;       GROUP8(LOADU_S, 0) }
                { int colbase = c * CHUNK + 512; GROUP8(LOADU_S, 0) }
            }
        }
    }

    // in-wave butterfly merge over the 3 seg bits
    WMERGE(ka0,ka1,ka2,ka3,ka4,ka5,ka6,ka7, 8)
    WMERGE(ka0,ka1,ka2,ka3,ka4,ka5,ka6,ka7, 16)
    WMERGE(ka0,ka1,ka2,ka3,ka4,ka5,ka6,ka7, 32)
    WMERGE(kb0,kb1,kb2,kb3,kb4,kb5,kb6,kb7, 8)
    WMERGE(kb0,kb1,kb2,kb3,kb4,kb5,kb6,kb7, 16)
    WMERGE(kb0,kb1,kb2,kb3,kb4,kb5,kb6,kb7, 32)

    int lane = tid & 63;
    int w    = tid >> 6;                          // wave 0..7
    if (lane < SLOTS) {
        shk[lane][w*8+0] = ka0; shk[lane][w*8+1] = ka1;
        shk[lane][w*8+2] = ka2; shk[lane][w*8+3] = ka3;
        shk[lane][w*8+4] = ka4; shk[lane][w*8+5] = ka5;
        shk[lane][w*8+6] = ka6; shk[lane][w*8+7] = ka7;
        shk[lane+SLOTS][w*8+0] = kb0; shk[lane+SLOTS][w*8+1] = kb1;
        shk[lane+SLOTS][w*8+2] = kb2; shk[lane+SLOTS][w*8+3] = kb3;
        shk[lane+SLOTS][w*8+4] = kb4; shk[lane+SLOTS][w*8+5] = kb5;
        shk[lane+SLOTS][w*8+6] = kb6; shk[lane+SLOTS][w*8+7] = kb7;
    }
    __syncthreads();

    if (tid < ROWS) {                              // one lane per row: 8 sorted lists -> 8
        int r = tid;
        int nn = rb * ROWS + r;
        float e0=BIGF,e1=BIGF,e2=BIGF,e3=BIGF,e4=BIGF,e5=BIGF,e6=BIGF,e7=BIGF;
        #pragma unroll
        for (int w2 = 0; w2 < 8; ++w2) {
            float b0 = shk[r][w2*8+0], b1 = shk[r][w2*8+1];
            float b2 = shk[r][w2*8+2], b3 = shk[r][w2*8+3];
            float b4 = shk[r][w2*8+4], b5 = shk[r][w2*8+5];
            float b6 = shk[r][w2*8+6], b7 = shk[r][w2*8+7];
            BMERGE8S(e0,e1,e2,e3,e4,e5,e6,e7, b0,b1,b2,b3,b4,b5,b6,b7)
        }

        // restore d2 = sqn + s for the selected 8
        float cn;
        if constexpr (USEF4) {
            cn = cp[nn].w;
        } else {
            size_t so = (size_t)(bN + nn) * 3;
            float xx = mu0[so], yy = mu0[so+1], zz = mu0[so+2];
            cn = (xx*xx + yy*yy) + zz*zz;
        }

        double s0 = sqrt(fmax((double)(cn + e0), 0.0)), s1 = sqrt(fmax((double)(cn + e1), 0.0));
        double s2 = sqrt(fmax((double)(cn + e2), 0.0)), s3 = sqrt(fmax((double)(cn + e3), 0.0));
        double s4 = sqrt(fmax((double)(cn + e4), 0.0)), s5 = sqrt(fmax((double)(cn + e5), 0.0));
        double s6 = sqrt(fmax((double)(cn + e6), 0.0)), s7 = sqrt(fmax((double)(cn + e7), 0.0));
        double d_mean = (((s0 + s1) + (s2 + s3)) + ((s4 + s5) + (s6 + s7))) / 8.0;

        double sigma = fmin(fmax(1.5 * d_mean, 1e-3), 100.0);
        double spacing = sigma * sigma + 1e-6;

        int p = (int)out[(size_t)B_ * N_ * 12 + (size_t)(bN + nn)];
        const float* S = Sig_p + (size_t)(b * K_ + p) * 9;
        double s00 = (double)S[0];
        double s01 = 0.5 * ((double)S[1] + (double)S[3]);
        double s02 = 0.5 * ((double)S[2] + (double)S[6]);
        double s11 = (double)S[4];
        double s12 = 0.5 * ((double)S[5] + (double)S[7]);
        double s22 = (double)S[8];

        const double BETA = 0.85;
        const double OMB  = 1.0 - 0.85;
        double nm = (double)node_mask[bN + nn];

        double d00 = (BETA * (s00 + 1e-6) + OMB * spacing) + 1e-6;
        double d11 = (BETA * (s11 + 1e-6) + OMB * spacing) + 1e-6;
        double d22 = (BETA * (s22 + 1e-6) + OMB * spacing) + 1e-6;
        double o01 = BETA * s01;
        double o02 = BETA * s02;
        double o12 = BETA * s12;

        float* Sg = out + (size_t)B_ * N_ * 3 + (size_t)(bN + nn) * 9;
        Sg[0] = (float)(d00 * nm); Sg[1] = (float)(o01 * nm); Sg[2] = (float)(o02 * nm);
        Sg[3] = (float)(o01 * nm); Sg[4] = (float)(d11 * nm); Sg[5] = (float)(o12 * nm);
        Sg[6] = (float)(o02 * nm); Sg[7] = (float)(o12 * nm); Sg[8] = (float)(d22 * nm);
    }
}

// ---------------- launch ----------------
extern "C" void kernel_launch(void* const* d_in, const int* in_sizes, int n_in,
                              void* d_out, int out_size, void* d_ws, size_t ws_size,
                              hipStream_t stream)
{
    const float* mu_p        = (const float*)d_in[0];
    const float* Sig_p       = (const float*)d_in[1];
    const float* occ         = (const float*)d_in[2];
    const float* mask_parent = (const float*)d_in[3];
    const float* node_mask   = (const float*)d_in[4];
    const float* z           = (const float*)d_in[5];
    float* out = (float*)d_out;

    // float4 mu0 copy (with squared norm in .w) lives in d_ws.
    int useF4 = (ws_size >= (size_t)B_ * N_ * sizeof(float4)) ? 1 : 0;
    float4* mu4 = (float4*)d_ws;

    fused_kernel<<<B_ * 8, 512, 0, stream>>>(mu_p, Sig_p, occ, mask_parent,
                                             node_mask, z, out, mu4, useF4);
    if (useF4)
        knn_kernel<1><<<B_ * (N_ / ROWS), KTHREADS, 0, stream>>>(Sig_p, node_mask, mu4, out);
    else
        knn_kernel<0><<<B_ * (N_ / ROWS), KTHREADS, 0, stream>>>(Sig_p, node_mask, mu4, out);
}